// Round 2
// baseline (2058.961 us; speedup 1.0000x reference)
//
#include <hip/hip_runtime.h>
#include <cstdio>
#include <cstdint>

typedef unsigned short u16;
typedef __bf16 bf16x8 __attribute__((ext_vector_type(8)));
typedef float f32x4 __attribute__((ext_vector_type(4)));

// problem constants
static const int EE = 1024;   // embed
static const int TT = 1024;   // seq len
static const int BB = 2;      // batch
static const int NTOK = 2048; // B*T
static const int HH = 16;     // heads
static const int DK = 64;
static const int FF = 4096;
static const int VV = 32000;
static const int LL = 6;

__device__ __forceinline__ float bf2f(u16 u) {
  unsigned int i = ((unsigned int)u) << 16;
  float f; __builtin_memcpy(&f, &i, 4); return f;
}
__device__ __forceinline__ u16 f2bf(float f) {
  unsigned int i; __builtin_memcpy(&i, &f, 4);
  unsigned int r = i + 0x7fffu + ((i >> 16) & 1u);
  return (u16)(r >> 16);
}

__device__ __forceinline__ void gll16(const u16* g, u16* l) {
  __builtin_amdgcn_global_load_lds(
      (__attribute__((address_space(1))) void*)(uintptr_t)g,
      (__attribute__((address_space(3))) void*)l,
      16, 0, 0);
}

// ---------------- embed: x = emb[idx] + pos  (fp32 in, fp32 out) ----------------
__global__ __launch_bounds__(256) void embed_k(const int* __restrict__ idx,
                                               const float* __restrict__ emb,
                                               const float* __restrict__ pos,
                                               float* __restrict__ x) {
  long i = (long)blockIdx.x * 256 + threadIdx.x;  // over NTOK*EE
  int n = (int)(i >> 10), e = (int)(i & 1023);
  int tok = idx[n];
  int t = n & (TT - 1);
  x[i] = emb[(long)tok * EE + e] + pos[(long)t * EE + e];
}

// ---------------- layernorm: fp32 x -> bf16 out ----------------
__global__ __launch_bounds__(256) void layernorm_k(const float* __restrict__ x,
                                                   const float* __restrict__ g,
                                                   const float* __restrict__ b,
                                                   u16* __restrict__ out) {
  int row = blockIdx.x * 4 + (threadIdx.x >> 6);
  int lane = threadIdx.x & 63;
  const float* xr = x + (long)row * EE;
  float v[16];
  float s = 0.f, s2 = 0.f;
#pragma unroll
  for (int j = 0; j < 16; j++) {
    float t = xr[j * 64 + lane];
    v[j] = t; s += t; s2 += t * t;
  }
#pragma unroll
  for (int o = 32; o; o >>= 1) { s += __shfl_xor(s, o); s2 += __shfl_xor(s2, o); }
  float mu = s * (1.f / EE);
  float var = s2 * (1.f / EE) - mu * mu;
  float rs = rsqrtf(var + 1e-5f);
  u16* orow = out + (long)row * EE;
#pragma unroll
  for (int j = 0; j < 16; j++) {
    int c = j * 64 + lane;
    orow[c] = f2bf((v[j] - mu) * rs * g[c] + b[c]);
  }
}

// ---------------- pack Wq/Wk/Wv (one layer, fp32) into bf16 B^T [3072][1024] ----------------
__global__ __launch_bounds__(256) void pack_qkvT_k(const float* __restrict__ Wq,
                                                   const float* __restrict__ Wk,
                                                   const float* __restrict__ Wv,
                                                   u16* __restrict__ out) {
  long base = ((long)blockIdx.x * 256 + threadIdx.x) * 4;  // over 3*EE*EE
  int c = (int)(base >> 10);
  int e0 = (int)(base & 1023);
  const float* W = (c < 1024) ? Wq : (c < 2048 ? Wk : Wv);
  int cm = c & 1023;
  int hh = cm >> 6, d = cm & 63;
#pragma unroll
  for (int i = 0; i < 4; i++) {
    int e = e0 + i;
    out[(long)c * EE + e] = f2bf(W[((long)hh * EE + e) * DK + d]);
  }
}

// ---------------- batched transpose: src[R,C] (f32 or bf16) -> bf16 dst[C,R] ----------------
template <typename ST>
__global__ __launch_bounds__(256) void transpose_to_bf16(const ST* __restrict__ src,
                                                         long s_z1, long s_z2, int zmod, int ld_s,
                                                         u16* __restrict__ dst,
                                                         long d_z, int ld_d, int R, int C) {
  __shared__ u16 t[32][33];
  int z = blockIdx.z;
  const ST* S = src + (z / zmod) * s_z1 + (z % zmod) * s_z2;
  u16* D = dst + (long)z * d_z;
  int c0 = blockIdx.x * 32, r0 = blockIdx.y * 32;
  int lx = threadIdx.x & 31, ly = threadIdx.x >> 5;
#pragma unroll
  for (int i = 0; i < 4; i++) {
    int r = r0 + ly + i * 8;
    ST val = S[(long)r * ld_s + c0 + lx];
    if constexpr (sizeof(ST) == 4) t[ly + i * 8][lx] = f2bf((float)val);
    else t[ly + i * 8][lx] = (u16)val;
  }
  __syncthreads();
#pragma unroll
  for (int i = 0; i < 4; i++) {
    int c = c0 + ly + i * 8;
    D[(long)c * ld_d + r0 + lx] = t[lx][ly + i * 8];
  }
}

// ---------------- causal softmax over scores rows (in place, bf16) ----------------
__global__ __launch_bounds__(256) void softmax_k(u16* __restrict__ sc) {
  int gid = blockIdx.x * 4 + (threadIdx.x >> 6);  // z*TT + t
  int lane = threadIdx.x & 63;
  int t = gid & (TT - 1);
  u16* row = sc + (long)gid * TT;
  const float scale = 0.03125f;  // 1/sqrt(E) = 1/32
  float v[16];
  float m = -1e30f;
#pragma unroll
  for (int j = 0; j < 16; j++) {
    int c = j * 64 + lane;
    float s = bf2f(row[c]) * scale;
    v[j] = (c <= t) ? s : -1e30f;
    m = fmaxf(m, v[j]);
  }
#pragma unroll
  for (int o = 32; o; o >>= 1) m = fmaxf(m, __shfl_xor(m, o));
  float sum = 0.f;
#pragma unroll
  for (int j = 0; j < 16; j++) {
    float p = (v[j] > -1e29f) ? __expf(v[j] - m) : 0.f;
    v[j] = p; sum += p;
  }
#pragma unroll
  for (int o = 32; o; o >>= 1) sum += __shfl_xor(sum, o);
  float r = 1.f / sum;
#pragma unroll
  for (int j = 0; j < 16; j++) row[j * 64 + lane] = f2bf(v[j] * r);
}

// ---------------- NT GEMM: C = A[M,K] @ BT[N,K]^T  (m97 structure) ----------------
// EPI: 0 = bf16 C=acc ; 1 = fp32 C=acc+bias (logits) ; 2 = bf16 C=relu(acc+bias) ;
//      3 = fp32 C += acc + bias (residual, in place)
// causal_mode: 0 none ; 1 skip tiles with n0 > m0+BM-1 ; 2 limit K to m0+BM
template <int EPI, int BN>
__global__ __launch_bounds__(256) void gemm_nt(
    const u16* __restrict__ A, long a_z1, long a_z2,
    const u16* __restrict__ BT, long b_z1, long b_z2,
    void* Cv, long c_z1, long c_z2,
    const float* __restrict__ bias,
    int M, int N, int K, int lda, int ldb, int ldc,
    int zmod, int causal_mode) {
  constexpr int BM = 128, BK = 32;
  constexpr int WM = (BN == 128) ? 2 : 4;  // waves along M
  constexpr int WN = 4 / WM;               // waves along N
  constexpr int WROWS = BM / WM;           // 64 or 32
  constexpr int WCOLS = BN / WN;           // 64
  constexpr int FM = WROWS / 16;           // 4 or 2
  constexpr int FN = WCOLS / 16;           // 4
  constexpr int ACH = BM * BK / 8 / 256;   // 2
  constexpr int BCH = BN * BK / 8 / 256;   // 2 or 1

  __shared__ u16 As[BM * BK];
  __shared__ u16 Bs[BN * BK];

  int m0 = blockIdx.x * BM;
  int n0 = blockIdx.y * BN;
  if (causal_mode == 1 && n0 > m0 + (BM - 1)) return;
  int z = blockIdx.z;
  const u16* Ab = A + (z / zmod) * a_z1 + (z % zmod) * a_z2;
  const u16* Bb = BT + (z / zmod) * b_z1 + (z % zmod) * b_z2;

  int tid = threadIdx.x;
  int lane = tid & 63;
  int wave = tid >> 6;
  int wm = wave / WN, wn = wave % WN;
  int fr = lane & 15, kg = lane >> 4;

  f32x4 zero = {0.f, 0.f, 0.f, 0.f};
  f32x4 acc[FM][FN];
#pragma unroll
  for (int m = 0; m < FM; m++)
#pragma unroll
    for (int n = 0; n < FN; n++) acc[m][n] = zero;

  int kmax = (causal_mode == 2) ? min(K, m0 + BM) : K;

  for (int k0 = 0; k0 < kmax; k0 += BK) {
#pragma unroll
    for (int i = 0; i < ACH; i++) {
      int c = i * 256 + tid;
      gll16(Ab + (long)(m0 + (c >> 2)) * lda + k0 + (c & 3) * 8, &As[c * 8]);
    }
#pragma unroll
    for (int i = 0; i < BCH; i++) {
      int c = i * 256 + tid;
      gll16(Bb + (long)(n0 + (c >> 2)) * ldb + k0 + (c & 3) * 8, &Bs[c * 8]);
    }
    __syncthreads();
    bf16x8 af[FM], bfr[FN];
#pragma unroll
    for (int m = 0; m < FM; m++)
      af[m] = *(const bf16x8*)&As[(wm * WROWS + m * 16 + fr) * BK + kg * 8];
#pragma unroll
    for (int n = 0; n < FN; n++)
      bfr[n] = *(const bf16x8*)&Bs[(wn * WCOLS + n * 16 + fr) * BK + kg * 8];
#pragma unroll
    for (int m = 0; m < FM; m++)
#pragma unroll
      for (int n = 0; n < FN; n++)
        acc[m][n] = __builtin_amdgcn_mfma_f32_16x16x32_bf16(af[m], bfr[n], acc[m][n], 0, 0, 0);
    __syncthreads();
  }

  // epilogue: D layout col = lane&15, row = (lane>>4)*4 + reg  [m89-verified]
  u16* C16 = (u16*)Cv;
  float* C32 = (float*)Cv;
  long cb = (z / zmod) * c_z1 + (z % zmod) * c_z2;
  int rowb = m0 + wm * WROWS, colb = n0 + wn * WCOLS;
#pragma unroll
  for (int m = 0; m < FM; m++) {
#pragma unroll
    for (int n = 0; n < FN; n++) {
      int gc = colb + n * 16 + fr;
      float bv = 0.f;
      if (EPI >= 1) bv = bias[gc];
#pragma unroll
      for (int r = 0; r < 4; r++) {
        int gr = rowb + m * 16 + kg * 4 + r;
        long ci = cb + (long)gr * ldc + gc;
        float val = acc[m][n][r];
        if (EPI == 0) C16[ci] = f2bf(val);
        else if (EPI == 1) C32[ci] = val + bv;
        else if (EPI == 2) C16[ci] = f2bf(fmaxf(val + bv, 0.f));
        else C32[ci] = C32[ci] + val + bv;
      }
    }
  }
}

extern "C" void kernel_launch(void* const* d_in, const int* in_sizes, int n_in,
                              void* d_out, int out_size, void* d_ws, size_t ws_size,
                              hipStream_t stream) {
  const int*   idx  = (const int*)d_in[0];
  const float* emb  = (const float*)d_in[1];
  const float* pos  = (const float*)d_in[2];
  const float* Wq   = (const float*)d_in[3];
  const float* Wk   = (const float*)d_in[4];
  const float* Wv   = (const float*)d_in[5];
  const float* Wp   = (const float*)d_in[6];
  const float* bp   = (const float*)d_in[7];
  const float* ln1g = (const float*)d_in[8];
  const float* ln1b = (const float*)d_in[9];
  const float* ln2g = (const float*)d_in[10];
  const float* ln2b = (const float*)d_in[11];
  const float* W1   = (const float*)d_in[12];
  const float* b1   = (const float*)d_in[13];
  const float* W2   = (const float*)d_in[14];
  const float* b2   = (const float*)d_in[15];
  const float* lnfg = (const float*)d_in[16];
  const float* lnfb = (const float*)d_in[17];
  const float* Wout = (const float*)d_in[18];
  const float* bout = (const float*)d_in[19];

  char* w = (char*)d_ws;
  size_t off = 0;
  auto alloc = [&](size_t bytes) {
    void* p = w + off;
    off += (bytes + 255) & ~(size_t)255;
    return p;
  };
  float* x   = (float*)alloc((size_t)NTOK * EE * 4);
  u16* h     = (u16*)alloc((size_t)NTOK * EE * 2);
  u16* qkv   = (u16*)alloc((size_t)NTOK * 3 * EE * 2);
  u16* vT    = (u16*)alloc((size_t)BB * HH * DK * TT * 2);
  u16* sc    = (u16*)alloc((size_t)BB * HH * TT * TT * 2);  // reused for WoutT at the end
  u16* o     = (u16*)alloc((size_t)NTOK * EE * 2);
  u16* mid   = (u16*)alloc((size_t)NTOK * FF * 2);
  u16* WqkvT = (u16*)alloc((size_t)3 * EE * EE * 2);
  u16* WpT   = (u16*)alloc((size_t)EE * EE * 2);
  u16* W1T   = (u16*)alloc((size_t)FF * EE * 2);
  u16* W2T   = (u16*)alloc((size_t)EE * FF * 2);
  if (off > ws_size) {
    fprintf(stderr, "kernel_launch: ws too small, need %zu have %zu\n", off, ws_size);
    return;
  }

  embed_k<<<NTOK * EE / 256, 256, 0, stream>>>(idx, emb, pos, x);

  for (int l = 0; l < LL; l++) {
    const size_t wqkv_off = (size_t)l * HH * EE * DK;
    layernorm_k<<<NTOK / 4, 256, 0, stream>>>(x, ln1g + l * EE, ln1b + l * EE, h);
    pack_qkvT_k<<<3 * EE * EE / 1024, 256, 0, stream>>>(Wq + wqkv_off, Wk + wqkv_off, Wv + wqkv_off, WqkvT);
    // qkv = h @ Wqkv  -> [2048, 3072]
    gemm_nt<0, 128><<<dim3(16, 24, 1), 256, 0, stream>>>(
        h, 0, 0, WqkvT, 0, 0, qkv, 0, 0, nullptr,
        NTOK, 3 * EE, EE, EE, EE, 3 * EE, 1, 0);
    // vT[z][d][t] from qkv v-part
    transpose_to_bf16<u16><<<dim3(2, 32, 32), 256, 0, stream>>>(
        qkv + 2 * EE, (long)TT * 3 * EE, 64, 16, 3 * EE,
        vT, (long)DK * TT, TT, TT, DK);
    // scores[z] = q[z] @ k[z]^T  (causal tile skip)
    gemm_nt<0, 128><<<dim3(8, 8, 32), 256, 0, stream>>>(
        qkv, (long)TT * 3 * EE, 64, qkv + EE, (long)TT * 3 * EE, 64,
        sc, (long)16 * TT * TT, (long)TT * TT, nullptr,
        TT, TT, DK, 3 * EE, 3 * EE, TT, 16, 1);
    softmax_k<<<BB * HH * TT / 4, 256, 0, stream>>>(sc);
    // o[z] = probs[z] @ v[z]   (K limited by causal row range)
    gemm_nt<0, 64><<<dim3(8, 1, 32), 256, 0, stream>>>(
        sc, (long)16 * TT * TT, (long)TT * TT, vT, (long)16 * DK * TT, (long)DK * TT,
        o, (long)TT * EE, 64, nullptr,
        TT, DK, TT, TT, TT, EE, 16, 2);
    // x += o @ Wp + bp
    transpose_to_bf16<float><<<dim3(32, 32, 1), 256, 0, stream>>>(
        Wp + (size_t)l * EE * EE, 0, 0, 1, EE, WpT, 0, EE, EE, EE);
    gemm_nt<3, 128><<<dim3(16, 8, 1), 256, 0, stream>>>(
        o, 0, 0, WpT, 0, 0, x, 0, 0, bp + l * EE,
        NTOK, EE, EE, EE, EE, EE, 1, 0);
    // MLP
    layernorm_k<<<NTOK / 4, 256, 0, stream>>>(x, ln2g + l * EE, ln2b + l * EE, h);
    transpose_to_bf16<float><<<dim3(FF / 32, EE / 32, 1), 256, 0, stream>>>(
        W1 + (size_t)l * EE * FF, 0, 0, 1, FF, W1T, 0, EE, EE, FF);
    gemm_nt<2, 128><<<dim3(16, 32, 1), 256, 0, stream>>>(
        h, 0, 0, W1T, 0, 0, mid, 0, 0, b1 + l * FF,
        NTOK, FF, EE, EE, EE, FF, 1, 0);
    transpose_to_bf16<float><<<dim3(EE / 32, FF / 32, 1), 256, 0, stream>>>(
        W2 + (size_t)l * FF * EE, 0, 0, 1, EE, W2T, 0, FF, FF, EE);
    gemm_nt<3, 128><<<dim3(16, 8, 1), 256, 0, stream>>>(
        mid, 0, 0, W2T, 0, 0, x, 0, 0, b2 + l * EE,
        NTOK, EE, FF, FF, FF, EE, 1, 0);
  }

  // final LN + logits
  layernorm_k<<<NTOK / 4, 256, 0, stream>>>(x, lnfg, lnfb, h);
  u16* WoutT = sc;  // 64 MB scores buffer holds the 62.5 MB WoutT
  transpose_to_bf16<float><<<dim3(VV / 32, EE / 32, 1), 256, 0, stream>>>(
      Wout, 0, 0, 1, VV, WoutT, 0, EE, EE, VV);
  gemm_nt<1, 128><<<dim3(16, 250, 1), 256, 0, stream>>>(
      h, 0, 0, WoutT, 0, 0, d_out, 0, 0, bout,
      NTOK, VV, EE, EE, EE, VV, 1, 0);
}